// Round 1
// baseline (120.836 us; speedup 1.0000x reference)
//
#include <hip/hip_runtime.h>

// Trilinear 3D-LUT interpolation (image-adaptive-3DLUT forward).
// lut: [3, 33, 33, 33] fp32, x: [4, 3, 1024, 1024] fp32 in [0,1], out same as x.
//
// Strategy: per-channel LUT (33^3 fp32 = 143.7 KB) fits in gfx950's 160 KB LDS.
// Each block = (channel c, pixel chunk). Stage lut[c] into LDS, stream pixels
// with float4 loads/stores, 8 LDS dword gathers per pixel (merge into ds_read2).
// Channel index interleaved over blockIdx so the 3 passes over the same x chunk
// run near-concurrently -> x re-reads hit L3 (256 MB), HBM sees x ~once.

#define LUT_D   33
#define LUT_N   (LUT_D * LUT_D * LUT_D)   // 35937
#define HW      (1024 * 1024)
#define HW4     (HW / 4)                  // 262144 float4 groups per plane
#define NGROUPS (4 * HW4)                 // 1048576 float4 groups per channel-pass
#define NCHUNKS 256
#define GROUPS_PER_BLOCK (NGROUPS / NCHUNKS)  // 4096
#define THREADS 1024
#define ITERS   (GROUPS_PER_BLOCK / THREADS)  // 4

__global__ __launch_bounds__(THREADS)
void lut3d_trilerp_kernel(const float* __restrict__ lut,
                          const float* __restrict__ x,
                          float* __restrict__ out) {
    extern __shared__ float slut[];  // LUT_N floats = 143748 B

    const int bx    = blockIdx.x;
    const int c     = bx % 3;        // output channel
    const int chunk = bx / 3;        // pixel chunk

    // Stage lut[c] into LDS (coalesced dword loads; mostly L2-hot after warmup).
    const float* lc = lut + c * LUT_N;
    for (int i = threadIdx.x; i < LUT_N; i += THREADS) {
        slut[i] = lc[i];
    }
    __syncthreads();

    const float4* x4 = (const float4*)x;
    float4*       o4 = (float4*)out;

    const int g0 = chunk * GROUPS_PER_BLOCK + (int)threadIdx.x;

#pragma unroll
    for (int it = 0; it < ITERS; ++it) {
        const int g     = g0 + it * THREADS;
        const int b_img = g >> 18;           // g / HW4  (HW4 = 2^18)
        const int hw4   = g & (HW4 - 1);
        const int ibase = b_img * 3 * HW4 + hw4;

        const float4 r4 = x4[ibase];
        const float4 g4 = x4[ibase + HW4];
        const float4 b4 = x4[ibase + 2 * HW4];

        const float rr[4] = {r4.x, r4.y, r4.z, r4.w};
        const float gg[4] = {g4.x, g4.y, g4.z, g4.w};
        const float bb[4] = {b4.x, b4.y, b4.z, b4.w};
        float oo[4];

#pragma unroll
        for (int k = 0; k < 4; ++k) {
            const float sr = rr[k] * 32.0f;
            const float sg = gg[k] * 32.0f;
            const float sb = bb[k] * 32.0f;
            // idx = clip(floor(s), 0, 31); d = s - idx   (matches reference)
            float fr = fminf(fmaxf(floorf(sr), 0.0f), 31.0f);
            float fg = fminf(fmaxf(floorf(sg), 0.0f), 31.0f);
            float fb = fminf(fmaxf(floorf(sb), 0.0f), 31.0f);
            const float dr = sr - fr;
            const float dg = sg - fg;
            const float db = sb - fb;
            const int ir = (int)fr, ig = (int)fg, ib = (int)fb;
            const int idx = (ib * LUT_D + ig) * LUT_D + ir;

            // 8 corners; r-neighbors adjacent -> ds_read2-friendly pairs.
            const float v000 = slut[idx];
            const float v001 = slut[idx + 1];
            const float v010 = slut[idx + LUT_D];
            const float v011 = slut[idx + LUT_D + 1];
            const float v100 = slut[idx + LUT_D * LUT_D];
            const float v101 = slut[idx + LUT_D * LUT_D + 1];
            const float v110 = slut[idx + LUT_D * LUT_D + LUT_D];
            const float v111 = slut[idx + LUT_D * LUT_D + LUT_D + 1];

            const float l00 = v000 + dr * (v001 - v000);
            const float l01 = v010 + dr * (v011 - v010);
            const float l10 = v100 + dr * (v101 - v100);
            const float l11 = v110 + dr * (v111 - v110);
            const float l0  = l00 + dg * (l01 - l00);
            const float l1  = l10 + dg * (l11 - l10);
            oo[k] = l0 + db * (l1 - l0);
        }

        o4[(b_img * 3 + c) * HW4 + hw4] = make_float4(oo[0], oo[1], oo[2], oo[3]);
    }
}

extern "C" void kernel_launch(void* const* d_in, const int* in_sizes, int n_in,
                              void* d_out, int out_size, void* d_ws, size_t ws_size,
                              hipStream_t stream) {
    const float* lut = (const float*)d_in[0];  // [3, 33, 33, 33]
    const float* x   = (const float*)d_in[1];  // [4, 3, 1024, 1024]
    float*       out = (float*)d_out;

    const int grid = 3 * NCHUNKS;  // 768 blocks: c = bx%3, chunk = bx/3
    const size_t lds_bytes = LUT_N * sizeof(float);  // 143748 B (<= 160 KB)

    lut3d_trilerp_kernel<<<grid, THREADS, lds_bytes, stream>>>(lut, x, out);
}